// Round 2
// baseline (1678.312 us; speedup 1.0000x reference)
//
#include <hip/hip_runtime.h>
#include <hip/hip_bf16.h>

#define N_PTS 131072
#define KC    512
#define DIM   64
#define MAXIT 5

// ---------------------------------------------------------------------------
// c2 kernel: c2[k] = sum_d C[k][d]^2   (squares rounded, then tree-sum —
// mimics np.sum(C*C, axis=1) pairwise structure)
// ---------------------------------------------------------------------------
__global__ __launch_bounds__(256) void c2_kernel(const float* __restrict__ C,
                                                 float* __restrict__ c2out) {
    int k = blockIdx.x * 256 + threadIdx.x;
    if (k < KC) {
        float sq[DIM];
        #pragma unroll
        for (int j = 0; j < DIM; ++j) {
            float c = C[k * DIM + j];
            sq[j] = c * c;
        }
        #pragma unroll
        for (int st = 1; st < DIM; st <<= 1)
            #pragma unroll
            for (int j = 0; j < DIM; j += 2 * st)
                sq[j] = sq[j] + sq[j + st];
        c2out[k] = sq[0];
    }
}

// ---------------------------------------------------------------------------
// assign kernel: one thread per point. Point held in 16 float4 VGPRs.
// Centers read via wave-uniform index -> scalar (s_load) path.
//
// d2 = (x2 + c2[k]) - 2*dot  — same op shape & magnitude as the reference,
// so the final f32 rounding (ULP ~7.6e-6 at |d2|~128) quantizes ties
// identically and first-index argmin tie-breaking matches np.
// (2*dot is exact in fp32, so fma contraction of the subtract is harmless.)
// ---------------------------------------------------------------------------
__global__ __launch_bounds__(256) void assign_kernel(
        const float* __restrict__ X, const float* __restrict__ C,
        const float* __restrict__ c2v,
        int* __restrict__ asn, float* __restrict__ out_f) {
    int n = blockIdx.x * 256 + threadIdx.x;

    float4 x[16];
    const float4* xp = (const float4*)(X + (size_t)n * DIM);
    #pragma unroll
    for (int j = 0; j < 16; ++j) x[j] = xp[j];

    // x2 = sum of squares, squares rounded first then tree-summed
    float sq[DIM];
    #pragma unroll
    for (int j = 0; j < 16; ++j) {
        sq[4 * j + 0] = x[j].x * x[j].x;
        sq[4 * j + 1] = x[j].y * x[j].y;
        sq[4 * j + 2] = x[j].z * x[j].z;
        sq[4 * j + 3] = x[j].w * x[j].w;
    }
    #pragma unroll
    for (int st = 1; st < DIM; st <<= 1)
        #pragma unroll
        for (int j = 0; j < DIM; j += 2 * st)
            sq[j] = sq[j] + sq[j + st];
    float x2 = sq[0];

    float best = 3.4e38f;
    int bi = 0;
    for (int k = 0; k < KC; ++k) {
        // force wave-uniform (SGPR) addressing for the center row
        int ku = __builtin_amdgcn_readfirstlane(k);
        const float* cp = C + (size_t)ku * DIM;
        float c2k = c2v[ku];
        float a0 = 0.f, a1 = 0.f, a2 = 0.f, a3 = 0.f;
        #pragma unroll
        for (int j = 0; j < 16; ++j) {
            a0 = fmaf(x[j].x, cp[4 * j + 0], a0);
            a1 = fmaf(x[j].y, cp[4 * j + 1], a1);
            a2 = fmaf(x[j].z, cp[4 * j + 2], a2);
            a3 = fmaf(x[j].w, cp[4 * j + 3], a3);
        }
        float dot = (a0 + a1) + (a2 + a3);
        float t = x2 + c2k;          // rounded at ~192 scale, matches np
        float d2 = t - 2.0f * dot;   // 2*dot exact; one rounding, matches np
        if (d2 < best) { best = d2; bi = k; }
    }
    asn[n] = bi;
    out_f[n] = (float)bi;   // harness reads assignments as float32
}

// ---------------------------------------------------------------------------
// accumulate kernel: 128 blocks = 32 point-chunks (4096 pts) x 4 dim-slices
// (16 dims). 32 KB LDS partial sums per block, flushed with global f32
// atomics. Counts accumulated once per point (slice 0, dim-lane 0).
// ---------------------------------------------------------------------------
__global__ __launch_bounds__(256) void accum_kernel(
        const float* __restrict__ X, const int* __restrict__ asn,
        float* __restrict__ sums, float* __restrict__ counts) {
    __shared__ float lsum[KC * 16];
    int slice = blockIdx.x & 3;     // which 16-dim slice
    int chunk = blockIdx.x >> 2;    // which 4096-point chunk
    int p  = threadIdx.x >> 4;      // 0..15 point within group
    int dd = threadIdx.x & 15;      // 0..15 dim within slice

    for (int i = threadIdx.x; i < KC * 16; i += 256) lsum[i] = 0.f;
    __syncthreads();

    int base = chunk * 4096;
    for (int t = 0; t < 4096; t += 16) {
        int n = base + t + p;
        int a = asn[n];
        float x = X[(size_t)n * DIM + slice * 16 + dd];
        unsafeAtomicAdd(&lsum[a * 16 + dd], x);
        if (slice == 0 && dd == 0) unsafeAtomicAdd(&counts[a], 1.0f);
    }
    __syncthreads();

    for (int i = threadIdx.x; i < KC * 16; i += 256) {
        float v = lsum[i];
        if (v != 0.f) {
            int k  = i >> 4;
            int d2 = i & 15;
            unsafeAtomicAdd(&sums[k * DIM + slice * 16 + d2], v);
        }
    }
}

// ---------------------------------------------------------------------------
// update kernel: new_centers = sums / max(counts,1); element-wise ==0 entries
// re-initialized from X[repl_idx[i]]. Writes working centers + d_out copy.
// ---------------------------------------------------------------------------
__global__ __launch_bounds__(256) void update_kernel(
        const float* __restrict__ sums, const float* __restrict__ counts,
        const int* __restrict__ repl, const float* __restrict__ X,
        float* __restrict__ Cws, float* __restrict__ outC) {
    int idx = blockIdx.x * 256 + threadIdx.x;   // < KC*DIM
    int k = idx >> 6;
    int d = idx & 63;
    float cnt = counts[k];
    float v = sums[idx] / fmaxf(cnt, 1.0f);
    if (v == 0.0f) v = X[(size_t)repl[k] * DIM + d];
    Cws[idx] = v;
    outC[idx] = v;
}

// ---------------------------------------------------------------------------
extern "C" void kernel_launch(void* const* d_in, const int* in_sizes, int n_in,
                              void* d_out, int out_size, void* d_ws, size_t ws_size,
                              hipStream_t stream) {
    const float* X    = (const float*)d_in[0];   // [N, D]
    const float* C0   = (const float*)d_in[1];   // [K, D]
    const int*   repl = (const int*)d_in[2];     // [MAXIT, K]
    float* out = (float*)d_out;                  // [N] assignments + [K*D] centers

    char* ws = (char*)d_ws;
    int*   asn     = (int*)(ws + 0);                       // 512 KB
    float* Cws     = (float*)(ws + 524288);                // 128 KB
    float* sums    = (float*)(ws + 524288 + 131072);       // 128 KB
    float* counts  = (float*)(ws + 524288 + 2 * 131072);   // 2 KB (adjacent to sums)
    float* c2v     = (float*)(ws + 524288 + 2 * 131072 + 2048); // 2 KB

    for (int i = 0; i < MAXIT; ++i) {
        const float* C = (i == 0) ? C0 : Cws;

        c2_kernel<<<2, 256, 0, stream>>>(C, c2v);

        assign_kernel<<<N_PTS / 256, 256, 0, stream>>>(X, C, c2v, asn, out);

        // zero sums (128 KB) + counts (2 KB), contiguous in ws
        hipMemsetAsync(sums, 0, (KC * DIM + KC) * sizeof(float), stream);

        accum_kernel<<<128, 256, 0, stream>>>(X, asn, sums, counts);

        update_kernel<<<(KC * DIM) / 256, 256, 0, stream>>>(
            sums, counts, repl + i * KC, X, Cws, out + N_PTS);
    }
}

// Round 5
// 806.735 us; speedup vs baseline: 2.0804x; 2.0804x over previous
//
#include <hip/hip_runtime.h>

#define N_PTS 131072
#define KC    512
#define DIM   64
#define MAXIT 5
#define KW    128                     // centers per wave (4 waves cover KC)
#define NCHUNK 64
#define CHUNK_PTS (N_PTS / NCHUNK)    // 2048
#define FIXSCALE 1099511627776.0      // 2^40

// ---------------------------------------------------------------------------
// c2 kernel (iter 0 only): c2[k] = sum_d C[k][d]^2, squares rounded then
// pairwise tree — identical value tree to round 2 (which passed).
// ---------------------------------------------------------------------------
__global__ __launch_bounds__(256) void c2_kernel(const float* __restrict__ C,
                                                 float* __restrict__ c2out) {
    int k = blockIdx.x * 256 + threadIdx.x;
    if (k < KC) {
        float sq[DIM];
        #pragma unroll
        for (int j = 0; j < DIM; ++j) {
            float c = C[k * DIM + j];
            sq[j] = c * c;
        }
        #pragma unroll
        for (int st = 1; st < DIM; st <<= 1)
            #pragma unroll
            for (int j = 0; j < DIM; j += 2 * st)
                sq[j] = sq[j] + sq[j + st];
        c2out[k] = sq[0];
    }
}

// ---------------------------------------------------------------------------
// assign kernel: block = 4 waves over the SAME 64 points (lane = point);
// wave w scans centers [128w, 128w+128). Cross-wave argmin combine via LDS
// u64 keys (monotone float map << 32 | k). Verbatim from round 4, which
// produced absmax 6.1e-5 (correct) — only the accumulation changed.
// ---------------------------------------------------------------------------
__global__ __launch_bounds__(256, 4) void assign_kernel(
        const float* __restrict__ X, const float* __restrict__ C,
        const float* __restrict__ c2v,
        int* __restrict__ asn, float* __restrict__ out_f) {
    __shared__ unsigned long long keys[3][64];   // waves 1..3 deposit here
    int w = threadIdx.x >> 6;
    int l = threadIdx.x & 63;
    int n = blockIdx.x * 64 + l;

    float4 x[16];
    const float4* xp = (const float4*)(X + (size_t)n * DIM);
    #pragma unroll
    for (int j = 0; j < 16; ++j) x[j] = xp[j];

    // x2: squares rounded first, then the round-2 pairwise tree (levels 0+1
    // fused; partials identical to round 2's sq-tree).
    float p[32];
    #pragma unroll
    for (int j = 0; j < 16; ++j) {
        float s0 = x[j].x * x[j].x;
        float s1 = x[j].y * x[j].y;
        float s2 = x[j].z * x[j].z;
        float s3 = x[j].w * x[j].w;
        p[2 * j]     = s0 + s1;
        p[2 * j + 1] = s2 + s3;
    }
    #pragma unroll
    for (int st = 1; st < 32; st <<= 1)
        #pragma unroll
        for (int j = 0; j < 32; j += 2 * st)
            p[j] = p[j] + p[j + st];
    float x2 = p[0];

    int k0 = w * KW;
    float best = 3.4e38f;
    int bi = k0;
    for (int k = k0; k < k0 + KW; ++k) {
        int ku = __builtin_amdgcn_readfirstlane(k);   // wave-uniform -> s_load
        const float* cp = C + (size_t)ku * DIM;
        float c2k = c2v[ku];
        float a0 = 0.f, a1 = 0.f, a2 = 0.f, a3 = 0.f;
        #pragma unroll
        for (int j = 0; j < 16; ++j) {
            a0 = fmaf(x[j].x, cp[4 * j + 0], a0);
            a1 = fmaf(x[j].y, cp[4 * j + 1], a1);
            a2 = fmaf(x[j].z, cp[4 * j + 2], a2);
            a3 = fmaf(x[j].w, cp[4 * j + 3], a3);
        }
        float dot = (a0 + a1) + (a2 + a3);
        float t  = x2 + c2k;          // rounded at d2's scale, matches np
        float d2 = t - 2.0f * dot;    // 2*dot exact
        if (d2 < best) { best = d2; bi = k; }
    }

    // sign-aware monotone float->u32 order map
    unsigned int b = __float_as_uint(best);
    b = (b & 0x80000000u) ? ~b : (b | 0x80000000u);
    unsigned long long key = ((unsigned long long)b << 32) | (unsigned int)bi;

    if (w > 0) keys[w - 1][l] = key;
    __syncthreads();
    if (w == 0) {
        #pragma unroll
        for (int g = 0; g < 3; ++g) {
            unsigned long long v = keys[g][l];
            if (v < key) key = v;
        }
        int k = (int)(unsigned int)key;
        asn[n] = k;
        out_f[n] = (float)k;
    }
}

// ---------------------------------------------------------------------------
// accumulate: 256 blocks = 64 chunks (2048 pts) x 4 dim-slices (16 dims).
// INT64 FIXED-POINT (scale 2^40) LDS + global atomics: integer addition is
// exactly order-independent -> bit-deterministic across graph replays (the
// round-4 tripwire failure was f32-atomic ordering nondeterminism).
// x -> round(x * 2^40) computed in double (exact for f32 inputs); max |sum|
// ~ 6 * 2^40 * 131072 ~ 8.6e17 < 2^63. Quantization error < 1e-9 per center
// element — invisible vs the 6.1e-5 passing margin.
// ---------------------------------------------------------------------------
__global__ __launch_bounds__(256) void accum_kernel(
        const float* __restrict__ X, const int* __restrict__ asn,
        unsigned long long* __restrict__ qsums, int* __restrict__ counts) {
    __shared__ unsigned long long lsum[KC * 16];   // 64 KB
    __shared__ int lcnt[KC];
    int slice = blockIdx.x & 3;
    int chunk = blockIdx.x >> 2;
    int p4 = threadIdx.x >> 2;   // 0..63: point lane
    int c4 = threadIdx.x & 3;    // float4 slot within the 16-dim slice

    for (int i = threadIdx.x; i < KC * 16; i += 256) lsum[i] = 0ull;
    for (int i = threadIdx.x; i < KC; i += 256) lcnt[i] = 0;
    __syncthreads();

    int base = chunk * CHUNK_PTS;
    #pragma unroll 2
    for (int it = 0; it < CHUNK_PTS / 64; ++it) {
        int n = base + it * 64 + p4;
        int a = asn[n];
        float4 xv = *(const float4*)(X + (size_t)n * DIM + slice * 16 + c4 * 4);
        long long q0 = (long long)llrint((double)xv.x * FIXSCALE);
        long long q1 = (long long)llrint((double)xv.y * FIXSCALE);
        long long q2 = (long long)llrint((double)xv.z * FIXSCALE);
        long long q3 = (long long)llrint((double)xv.w * FIXSCALE);
        atomicAdd(&lsum[a * 16 + c4 * 4 + 0], (unsigned long long)q0);
        atomicAdd(&lsum[a * 16 + c4 * 4 + 1], (unsigned long long)q1);
        atomicAdd(&lsum[a * 16 + c4 * 4 + 2], (unsigned long long)q2);
        atomicAdd(&lsum[a * 16 + c4 * 4 + 3], (unsigned long long)q3);
        if (slice == 0 && c4 == 0) atomicAdd(&lcnt[a], 1);
    }
    __syncthreads();

    for (int i = threadIdx.x; i < KC * 16; i += 256) {
        unsigned long long v = lsum[i];
        if (v != 0ull) {
            int k  = i >> 4;
            int dd = i & 15;
            atomicAdd(&qsums[k * DIM + slice * 16 + dd], v);
        }
    }
    if (slice == 0)
        for (int i = threadIdx.x; i < KC; i += 256) {
            int v = lcnt[i];
            if (v != 0) atomicAdd(&counts[i], v);
        }
}

// ---------------------------------------------------------------------------
// update: new_centers = sums / max(counts,1); element-wise ==0 entries
// re-seeded from X[repl_idx[i]]. Fuses next iteration's c2 via butterfly
// shuffle (identical summation tree to c2_kernel). One wave per cluster.
// ---------------------------------------------------------------------------
__global__ __launch_bounds__(256) void update_kernel(
        const unsigned long long* __restrict__ qsums,
        const int* __restrict__ counts,
        const int* __restrict__ repl, const float* __restrict__ X,
        float* __restrict__ Cws, float* __restrict__ outC,
        float* __restrict__ c2v) {
    int k = blockIdx.x * 4 + (threadIdx.x >> 6);
    int d = threadIdx.x & 63;

    long long q = (long long)qsums[k * DIM + d];
    float s = (float)((double)q * (1.0 / FIXSCALE));
    float cnt = (float)counts[k];
    float v = s / fmaxf(cnt, 1.0f);
    if (v == 0.0f) v = X[(size_t)repl[k] * DIM + d];
    Cws[k * DIM + d]  = v;
    outC[k * DIM + d] = v;

    float sq = v * v;
    #pragma unroll
    for (int st = 1; st < 64; st <<= 1)
        sq += __shfl_xor(sq, st, 64);
    if (d == 0) c2v[k] = sq;
}

// ---------------------------------------------------------------------------
extern "C" void kernel_launch(void* const* d_in, const int* in_sizes, int n_in,
                              void* d_out, int out_size, void* d_ws, size_t ws_size,
                              hipStream_t stream) {
    const float* X    = (const float*)d_in[0];   // [N, D]
    const float* C0   = (const float*)d_in[1];   // [K, D]
    const int*   repl = (const int*)d_in[2];     // [MAXIT, K]
    float* out = (float*)d_out;                  // [N] assignments + [K*D] centers

    // Total ws footprint: 900 KB (round 2's 920 KB proved safe; round 3's
    // 12.8 MB failed with poison-pattern errors -> keep it small).
    char* ws = (char*)d_ws;
    int*   asn    = (int*)  (ws + 0);                        // 512 KB
    float* Cws    = (float*)(ws + (512 << 10));              // 128 KB
    unsigned long long* qsums = (unsigned long long*)(ws + (640 << 10)); // 256 KB
    int*   counts = (int*)  (ws + (896 << 10));              // 2 KB (contiguous w/ qsums)
    float* c2v    = (float*)(ws + (898 << 10));              // 2 KB

    c2_kernel<<<2, 256, 0, stream>>>(C0, c2v);

    for (int i = 0; i < MAXIT; ++i) {
        const float* C = (i == 0) ? C0 : Cws;

        assign_kernel<<<N_PTS / 64, 256, 0, stream>>>(X, C, c2v, asn, out);

        // zero qsums (256 KB) + counts (2 KB), contiguous
        hipMemsetAsync(qsums, 0, KC * DIM * sizeof(unsigned long long)
                                 + KC * sizeof(int), stream);

        accum_kernel<<<NCHUNK * 4, 256, 0, stream>>>(X, asn, qsums, counts);

        update_kernel<<<KC / 4, 256, 0, stream>>>(
            qsums, counts, repl + i * KC, X, Cws, out + N_PTS, c2v);
    }
}